// Round 3
// baseline (504.721 us; speedup 1.0000x reference)
//
#include <hip/hip_runtime.h>
#include <math.h>

typedef __attribute__((ext_vector_type(8))) _Float16 half8;
typedef __attribute__((ext_vector_type(4))) float float4_t;

#define NB 2048
#define LL 200
#define DD 128
#define AA 64
#define NEG_INF_F -4294967295.0f  // rounds to -2^32 in fp32, matches reference

#define WC_STRIDE 264   // 256 + 8 halves pad (528 B, multiple of 16 B -> b128 aligned, breaks bank pow2)
#define H1_STRIDE 72    // 64 + 8

// ws layout (bytes):
//   [0, 33792)          fp16 WcT, padded [64][WC_STRIDE]   (pad cols never read)
//   [33792, 43008)      fp16 W2T, [64][72] padded? -> stored dense [64][64] = 8192 B (+1024 slack)
//   [43008, 43008+512K) fp32 qA [2048][64]
#define WS_WC_BYTES   33792
#define WS_W2T_OFF    33792
#define WS_QA_OFF     43008

// ---------------- K1: weight transforms + qA ----------------
// blocks 0..127 : qA for 16 batches each
// block  128    : WcT = [[W1b - W1c]; [W1d]] transposed -> fp16 [a][k], padded rows
// block  129    : W2T fp16 [c][a]
__global__ __launch_bounds__(256)
void din_prep(const float* __restrict__ query,
              const float* __restrict__ W1,
              const float* __restrict__ b1,
              const float* __restrict__ W2,
              _Float16* __restrict__ ws16,
              float* __restrict__ qa)
{
    const int tid = threadIdx.x;
    const int blk = blockIdx.x;

    if (blk < 128) {
        __shared__ float sW1s[DD * AA];   // W1a + W1c  (32 KB)
        __shared__ float sq[16 * DD];     // 16 queries (8 KB)
        const int b0 = blk * 16;
        for (int i = tid; i < DD * AA; i += 256)
            sW1s[i] = W1[i] + W1[2 * DD * AA + i];
        for (int i = tid; i < 16 * DD; i += 256)
            sq[i] = query[(size_t)b0 * DD + i];
        __syncthreads();
        const int lane = tid & 63, bb = tid >> 6;
        for (int g = 0; g < 4; ++g) {
            const int bi = bb * 4 + g;
            float acc = b1[lane];
            #pragma unroll 8
            for (int d = 0; d < DD; ++d)
                acc += sq[bi * DD + d] * sW1s[d * AA + lane];
            qa[(size_t)(b0 + bi) * AA + lane] = acc;
        }
    } else if (blk == 128) {
        // WcT[a][k]: k<128 -> W1b-W1c ; k>=128 -> W1d.  Both need W1[(256+k)*64+a].
        const int a = tid >> 2, c = tid & 3, k0 = c * 64;
        for (int kk = 0; kk < 8; ++kk) {
            half8 v;
            #pragma unroll
            for (int j = 0; j < 8; ++j) {
                const int k = k0 + kk * 8 + j;
                float x;
                if (k < DD) x = W1[(DD + k) * AA + a] - W1[(2 * DD + k) * AA + a];
                else        x = W1[(2 * DD + k) * AA + a];
                v[j] = (_Float16)x;
            }
            *(half8*)&ws16[a * WC_STRIDE + k0 + kk * 8] = v;
        }
    } else {
        // W2T[c][a] dense 64x64 fp16
        _Float16* w2t = ws16 + WS_W2T_OFF / 2;
        const int c = tid >> 2, j0 = (tid & 3) * 16;
        for (int ch = 0; ch < 2; ++ch) {
            half8 v;
            #pragma unroll
            for (int j = 0; j < 8; ++j) {
                const int a = j0 + ch * 8 + j;
                v[j] = (_Float16)W2[a * AA + c];
            }
            *(half8*)&w2t[c * AA + j0 + ch * 8] = v;
        }
    }
}

// ---------------- K2: scores + softmax + weighted sum ----------------
// 1024 blocks x 256 thr. 4 waves = 2 batch rows, 2 waves per row (tiles t = sub + 2*i).
// GEMM1: K=256, A = [k | q*k] built on the fly; B = WcT from LDS.
// GEMM2: B = W2T held in registers. Layer3 in-register + shfl reduce.
__global__ __launch_bounds__(256, 3)
void din_main(const float* __restrict__ keys,
              const int*   __restrict__ keys_length,
              const float* __restrict__ a1p,
              const float* __restrict__ b2,
              const float* __restrict__ a2p,
              const float* __restrict__ W3,
              const _Float16* __restrict__ ws16,
              const float* __restrict__ qa,
              const float* __restrict__ query,
              float* __restrict__ out,
              float* __restrict__ att)
{
    __shared__ __align__(16) _Float16 sWc[AA * WC_STRIDE];      // 33792 B
    __shared__ __align__(16) _Float16 sH1[4 * 16 * H1_STRIDE];  //  9216 B (reused as float2 scratch)
    __shared__ float sS[2 * 224];                               //  1792 B

    const int tid  = threadIdx.x;
    const int lane = tid & 63, wv = tid >> 6;
    const int col  = lane & 15, quad = lane >> 4;
    const int p = wv >> 1, sub = wv & 1;          // pair index / sub-wave
    const int b = blockIdx.x * 2 + p;
    const int len = keys_length[b];
    const float pa1 = a1p[0], pa2 = a2p[0];

    // stage WcT (pure contiguous copy; pad columns carried along, never read)
    for (int i = tid; i < WS_WC_BYTES / 16; i += 256)
        ((int4*)sWc)[i] = ((const int4*)ws16)[i];
    for (int i = tid; i < 448; i += 256) sS[i] = NEG_INF_F;
    __syncthreads();

    // per-wave register preloads
    const _Float16* w2t = ws16 + WS_W2T_OFF / 2;
    half8 w2f[2][4];
    #pragma unroll
    for (int ks = 0; ks < 2; ++ks)
        #pragma unroll
        for (int n = 0; n < 4; ++n)
            w2f[ks][n] = *(const half8*)&w2t[(n * 16 + col) * AA + ks * 32 + quad * 8];

    float qareg[4], b2reg[4], w3reg[4];
    #pragma unroll
    for (int n = 0; n < 4; ++n) {
        qareg[n] = qa[(size_t)b * AA + n * 16 + col];
        b2reg[n] = b2[n * 16 + col];
        w3reg[n] = W3[n * 16 + col];
    }
    // q chunks for the q*k fragments: q[d], d = ks*32 + quad*8 + j (quad-dependent only)
    float qf[4][8];
    #pragma unroll
    for (int ks = 0; ks < 4; ++ks) {
        const float4 q0 = *(const float4*)(query + (size_t)b * DD + ks * 32 + quad * 8);
        const float4 q1 = *(const float4*)(query + (size_t)b * DD + ks * 32 + quad * 8 + 4);
        qf[ks][0] = q0.x; qf[ks][1] = q0.y; qf[ks][2] = q0.z; qf[ks][3] = q0.w;
        qf[ks][4] = q1.x; qf[ks][5] = q1.y; qf[ks][6] = q1.z; qf[ks][7] = q1.w;
    }

    const int ntiles = (len + 15) >> 4;
    _Float16* const myH = &sH1[wv * 16 * H1_STRIDE];

    for (int t = sub; t < ntiles; t += 2) {
        const int l0 = t * 16;
        const int lrow = l0 + col < LL ? l0 + col : LL - 1;  // clamp; masked later
        const float* const krow = keys + ((size_t)b * LL + lrow) * DD + quad * 8;

        // issue all 8 key loads up front
        float4 kv[8];
        #pragma unroll
        for (int ks = 0; ks < 4; ++ks) {
            kv[2 * ks]     = *(const float4*)(krow + ks * 32);
            kv[2 * ks + 1] = *(const float4*)(krow + ks * 32 + 4);
        }

        // ---- GEMM1: C(16x64) = [k | q*k](16x256) @ Wc(256x64) ----
        float4_t C[4] = {{0,0,0,0},{0,0,0,0},{0,0,0,0},{0,0,0,0}};
        #pragma unroll
        for (int ks = 0; ks < 4; ++ks) {
            half8 afk, afq;
            #pragma unroll
            for (int j = 0; j < 4; ++j) {
                const float ke0 = ((const float*)&kv[2 * ks])[j];
                const float ke1 = ((const float*)&kv[2 * ks + 1])[j];
                afk[j]     = (_Float16)ke0;
                afk[4 + j] = (_Float16)ke1;
                afq[j]     = (_Float16)(qf[ks][j] * ke0);
                afq[4 + j] = (_Float16)(qf[ks][4 + j] * ke1);
            }
            const int ko = ks * 32 + quad * 8;
            #pragma unroll
            for (int n = 0; n < 4; ++n) {
                const half8 bfk = *(const half8*)&sWc[(n * 16 + col) * WC_STRIDE + ko];
                C[n] = __builtin_amdgcn_mfma_f32_16x16x32_f16(afk, bfk, C[n], 0, 0, 0);
            }
            #pragma unroll
            for (int n = 0; n < 4; ++n) {
                const half8 bfq = *(const half8*)&sWc[(n * 16 + col) * WC_STRIDE + DD + ko];
                C[n] = __builtin_amdgcn_mfma_f32_16x16x32_f16(afq, bfq, C[n], 0, 0, 0);
            }
        }
        // epilogue: +qA, PReLU(a1) -> myH [m][a]
        #pragma unroll
        for (int n = 0; n < 4; ++n)
            #pragma unroll
            for (int r = 0; r < 4; ++r) {
                float v = C[n][r] + qareg[n];
                v = v >= 0.f ? v : pa1 * v;
                myH[(quad * 4 + r) * H1_STRIDE + n * 16 + col] = (_Float16)v;
            }

        // ---- GEMM2: D(16x64) = h1(16x64) @ W2(64x64), B from registers ----
        float4_t D[4] = {{0,0,0,0},{0,0,0,0},{0,0,0,0},{0,0,0,0}};
        #pragma unroll
        for (int ks = 0; ks < 2; ++ks) {
            const half8 af = *(const half8*)&myH[col * H1_STRIDE + ks * 32 + quad * 8];
            #pragma unroll
            for (int n = 0; n < 4; ++n)
                D[n] = __builtin_amdgcn_mfma_f32_16x16x32_f16(af, w2f[ks][n], D[n], 0, 0, 0);
        }
        // layer3: +b2, PReLU(a2), dot W3; reduce across 16 col-lanes (b3 dropped: shift-inv)
        float pr[4] = {0.f, 0.f, 0.f, 0.f};
        #pragma unroll
        for (int n = 0; n < 4; ++n)
            #pragma unroll
            for (int r = 0; r < 4; ++r) {
                float v = D[n][r] + b2reg[n];
                v = v >= 0.f ? v : pa2 * v;
                pr[r] += v * w3reg[n];
            }
        #pragma unroll
        for (int r = 0; r < 4; ++r) {
            float pv = pr[r];
            pv += __shfl_xor(pv, 1);
            pv += __shfl_xor(pv, 2);
            pv += __shfl_xor(pv, 4);
            pv += __shfl_xor(pv, 8);
            const int l = l0 + quad * 4 + r;
            if (col == 0 && l < len) sS[p * 224 + l] = pv;
        }
    }

    __syncthreads();

    // ---- wave-local softmax over this pair's 200 scores (both waves compute; sub==0 writes) ----
    float sv[4];
    #pragma unroll
    for (int j = 0; j < 4; ++j) {
        const int l = lane + 64 * j;
        sv[j] = (l < LL) ? sS[p * 224 + l] : -INFINITY;
    }
    float m = fmaxf(fmaxf(sv[0], sv[1]), fmaxf(sv[2], sv[3]));
    #pragma unroll
    for (int o = 1; o < 64; o <<= 1) m = fmaxf(m, __shfl_xor(m, o));
    float e[4], s = 0.f;
    #pragma unroll
    for (int j = 0; j < 4; ++j) {
        const int l = lane + 64 * j;
        e[j] = (l < LL) ? expf(sv[j] - m) : 0.f;
        s += e[j];
    }
    #pragma unroll
    for (int o = 1; o < 64; o <<= 1) s += __shfl_xor(s, o);
    const float inv = 1.f / s;   // len==0: all scores NEG_INF -> e=1, s=200 -> uniform (matches ref)
    if (sub == 0) {
        #pragma unroll
        for (int j = 0; j < 4; ++j) {
            const int l = lane + 64 * j;
            if (l < LL) {
                const float v = e[j] * inv;
                sS[p * 224 + l] = v;
                att[(size_t)b * LL + l] = v;
            }
        }
    }
    __syncthreads();

    // ---- weighted sum: pair splits rows (l % 2 == sub); combine via LDS ----
    const int Lcap = (len == 0) ? LL : len;
    float2 acc = make_float2(0.f, 0.f);
    const float* kb = keys + (size_t)b * LL * DD + (lane << 1);
    for (int l = sub; l < Lcap; l += 2) {
        const float w = sS[p * 224 + l];
        const float2 kv2 = *(const float2*)(kb + (size_t)l * DD);
        acc.x += w * kv2.x; acc.y += w * kv2.y;
    }
    float2* const sPS = (float2*)sH1;
    sPS[wv * 64 + lane] = acc;
    __syncthreads();
    if (sub == 0) {
        const float2 p0 = sPS[(2 * p) * 64 + lane];
        const float2 p1 = sPS[(2 * p + 1) * 64 + lane];
        float2 rr; rr.x = p0.x + p1.x; rr.y = p0.y + p1.y;
        *(float2*)(out + (size_t)b * DD + (lane << 1)) = rr;
    }
}

extern "C" void kernel_launch(void* const* d_in, const int* in_sizes, int n_in,
                              void* d_out, int out_size, void* d_ws, size_t ws_size,
                              hipStream_t stream) {
    (void)in_sizes; (void)n_in; (void)ws_size; (void)out_size;
    const float* query = (const float*)d_in[0];
    const float* keys  = (const float*)d_in[1];
    const int*   klen  = (const int*)d_in[2];
    const float* W1    = (const float*)d_in[3];
    const float* b1    = (const float*)d_in[4];
    const float* a1    = (const float*)d_in[5];
    const float* W2    = (const float*)d_in[6];
    const float* b2    = (const float*)d_in[7];
    const float* a2    = (const float*)d_in[8];
    const float* W3    = (const float*)d_in[9];
    // d_in[10] = b3: irrelevant to both outputs (softmax shift invariance)

    _Float16* ws16 = (_Float16*)d_ws;
    float*    qawk = (float*)((char*)d_ws + WS_QA_OFF);

    float* out = (float*)d_out;                  // (B, D) fp32
    float* att = out + (size_t)NB * DD;          // (B, L) fp32

    hipLaunchKernelGGL(din_prep, dim3(130), dim3(256), 0, stream,
                       query, W1, b1, W2, ws16, qawk);
    hipLaunchKernelGGL(din_main, dim3(NB / 2), dim3(256), 0, stream,
                       keys, klen, a1, b2, a2, W3, ws16, qawk, query, out, att);
}

// Round 4
// 325.584 us; speedup vs baseline: 1.5502x; 1.5502x over previous
//
#include <hip/hip_runtime.h>
#include <math.h>

typedef __attribute__((ext_vector_type(8))) _Float16 half8;
typedef __attribute__((ext_vector_type(4))) float float4_t;

#define NB 2048
#define LL 200
#define DD 128
#define AA 64
#define NEG_INF_F -4294967295.0f  // rounds to -2^32 in fp32, matches reference

#define WQ_STRIDE 136   // halves: 128 + 8 pad; 272 B row, 16B-aligned chunks

// ws layout (halves):
//   wbc16 [64][136] @ 0      : fp16 (W1b - W1c)^T, row a, padded
//   w1d16 [64][136] @ 8704   : fp16 W1d^T, row a, padded
//   W2T   [64][64]  @ 17408  : fp16 W2 transposed [c][a]
//   qa fp32 @ byte 43008     : [2048][64]  b1 + q@(W1a+W1c)
#define WS_WBC_H  0
#define WS_W1D_H  8704
#define WS_W2T_H  17408
#define WS_QA_OFF 43008

// ---------------- K1: weight transforms + qA ----------------
__global__ __launch_bounds__(256)
void din_prep(const float* __restrict__ query,
              const float* __restrict__ W1,
              const float* __restrict__ b1,
              const float* __restrict__ W2,
              _Float16* __restrict__ ws16,
              float* __restrict__ qa)
{
    const int tid = threadIdx.x;
    const int blk = blockIdx.x;

    if (blk < 128) {
        __shared__ float sW1s[DD * AA];   // W1a + W1c
        __shared__ float sq[16 * DD];
        const int b0 = blk * 16;
        for (int i = tid; i < DD * AA; i += 256)
            sW1s[i] = W1[i] + W1[2 * DD * AA + i];
        for (int i = tid; i < 16 * DD; i += 256)
            sq[i] = query[(size_t)b0 * DD + i];
        __syncthreads();
        const int lane = tid & 63, bb = tid >> 6;
        for (int g = 0; g < 4; ++g) {
            const int bi = bb * 4 + g;
            float acc = b1[lane];
            #pragma unroll 8
            for (int d = 0; d < DD; ++d)
                acc += sq[bi * DD + d] * sW1s[d * AA + lane];
            qa[(size_t)(b0 + bi) * AA + lane] = acc;
        }
    } else if (blk == 128) {
        // wbc16[a][d] = W1b - W1c ; w1d16[a][d] = W1d ; pad cols 128..135 = 0
        for (int i = tid; i < 64 * 17; i += 256) {
            const int a = i / 17, c = i - a * 17;
            half8 hb, hd;
            if (c == 16) {
                #pragma unroll
                for (int j = 0; j < 8; ++j) { hb[j] = (_Float16)0.f; hd[j] = (_Float16)0.f; }
            } else {
                const int d0 = c * 8;
                #pragma unroll
                for (int j = 0; j < 8; ++j) {
                    const int d = d0 + j;
                    hb[j] = (_Float16)(W1[(DD + d) * AA + a] - W1[(2 * DD + d) * AA + a]);
                    hd[j] = (_Float16)(W1[(3 * DD + d) * AA + a]);
                }
            }
            *(half8*)&ws16[WS_WBC_H + a * WQ_STRIDE + c * 8] = hb;
            *(half8*)&ws16[WS_W1D_H + a * WQ_STRIDE + c * 8] = hd;
        }
    } else {
        // W2T[c][a] dense 64x64 fp16
        _Float16* w2t = ws16 + WS_W2T_H;
        const int c = tid >> 2, j0 = (tid & 3) * 16;
        for (int ch = 0; ch < 2; ++ch) {
            half8 v;
            #pragma unroll
            for (int j = 0; j < 8; ++j)
                v[j] = (_Float16)W2[(j0 + ch * 8 + j) * AA + c];
            *(half8*)&w2t[c * AA + j0 + ch * 8] = v;
        }
    }
}

// ---------------- K2: one batch per block; keys read ONCE into LDS fp16 ----------------
// sKeys swizzle: 8-half chunk ci of row l stored at column-chunk (ci ^ (l&7)), stride 128.
__global__ __launch_bounds__(256, 2)
void din_main(const float* __restrict__ keys,
              const int*   __restrict__ keys_length,
              const float* __restrict__ a1p,
              const float* __restrict__ b2,
              const float* __restrict__ a2p,
              const float* __restrict__ W3,
              const _Float16* __restrict__ ws16,
              const float* __restrict__ qa,
              const float* __restrict__ query,
              float* __restrict__ out,
              float* __restrict__ att)
{
    __shared__ __align__(16) _Float16 sKeys[LL * DD];        // 51200 B
    __shared__ __align__(16) _Float16 sWq[AA * WQ_STRIDE];   // 17408 B (float scratch later)
    __shared__ __align__(16) _Float16 sH1[4 * 16 * 72];      //  9216 B
    __shared__ float sQ[136];
    __shared__ float sS[224];
    __shared__ float sRed[16];

    const int tid  = threadIdx.x;
    const int lane = tid & 63, wv = tid >> 6;
    const int col  = lane & 15, quad = lane >> 4;
    const int b    = blockIdx.x;
    const int len  = keys_length[b];
    const float pa1 = a1p[0], pa2 = a2p[0];
    const int Lcap = (len == 0) ? LL : len;   // len==0 -> uniform att over all 200 rows

    if (tid < 136) sQ[tid] = (tid < 128) ? query[(size_t)b * DD + tid] : 0.f;
    for (int i = tid; i < 224; i += 256) sS[i] = NEG_INF_F;
    __syncthreads();

    // ---- build sWq[a][d] = wbc + q[d]*w1d  (coalesced fp16 reads, L3-hot) ----
    for (int ci = tid; ci < 64 * 17; ci += 256) {
        const int c = ci % 17;
        const int d0 = c * 8;                 // c==16 -> pad chunk, sQ[128..135]==0
        const half8 hb = *(const half8*)&ws16[WS_WBC_H + ci * 8];
        const half8 hd = *(const half8*)&ws16[WS_W1D_H + ci * 8];
        half8 r;
        #pragma unroll
        for (int j = 0; j < 8; ++j)
            r[j] = (_Float16)((float)hb[j] + sQ[d0 + j] * (float)hd[j]);
        *(half8*)&sWq[ci * 8] = r;
    }
    // ---- stage keys rows [0, Lcap) coalesced -> fp16 swizzled LDS ----
    for (int i = tid; i < Lcap * 16; i += 256) {
        const int l = i >> 4, c8 = i & 15;
        const float* kp = keys + ((size_t)b * LL + l) * DD + c8 * 8;
        const float4 v0 = *(const float4*)kp;
        const float4 v1 = *(const float4*)(kp + 4);
        half8 h;
        h[0] = (_Float16)v0.x; h[1] = (_Float16)v0.y; h[2] = (_Float16)v0.z; h[3] = (_Float16)v0.w;
        h[4] = (_Float16)v1.x; h[5] = (_Float16)v1.y; h[6] = (_Float16)v1.z; h[7] = (_Float16)v1.w;
        *(half8*)&sKeys[l * DD + ((c8 ^ (l & 7)) << 3)] = h;
    }
    __syncthreads();

    // ---- per-lane constants ----
    const _Float16* w2t = ws16 + WS_W2T_H;
    half8 w2f[2][4];
    #pragma unroll
    for (int ks = 0; ks < 2; ++ks)
        #pragma unroll
        for (int n = 0; n < 4; ++n)
            w2f[ks][n] = *(const half8*)&w2t[(n * 16 + col) * AA + ks * 32 + quad * 8];
    float qareg[4], b2reg[4], w3reg[4];
    #pragma unroll
    for (int n = 0; n < 4; ++n) {
        qareg[n] = qa[(size_t)b * AA + n * 16 + col];
        b2reg[n] = b2[n * 16 + col];
        w3reg[n] = W3[n * 16 + col];
    }

    const int ntiles = (len + 15) >> 4;
    _Float16* const myH = &sH1[wv * 16 * 72];

    for (int t = wv; t < ntiles; t += 4) {
        const int l0 = t * 16;
        const int lr = (l0 + col < LL) ? (l0 + col) : (LL - 1);  // clamp; masked later

        // ---- GEMM1: C(16x64) = keys(16x128) @ Wq(128x64), A from swizzled LDS ----
        float4_t C[4] = {{0,0,0,0},{0,0,0,0},{0,0,0,0},{0,0,0,0}};
        #pragma unroll
        for (int ks = 0; ks < 4; ++ks) {
            const int swz = ((ks * 4 + quad) ^ (lr & 7)) << 3;
            const half8 af = *(const half8*)&sKeys[lr * DD + swz];
            const int ko = ks * 32 + quad * 8;
            #pragma unroll
            for (int n = 0; n < 4; ++n) {
                const half8 bf = *(const half8*)&sWq[(n * 16 + col) * WQ_STRIDE + ko];
                C[n] = __builtin_amdgcn_mfma_f32_16x16x32_f16(af, bf, C[n], 0, 0, 0);
            }
        }
        // epilogue: +qA, PReLU(a1) -> myH [m][a]
        #pragma unroll
        for (int n = 0; n < 4; ++n)
            #pragma unroll
            for (int r = 0; r < 4; ++r) {
                float v = C[n][r] + qareg[n];
                v = v >= 0.f ? v : pa1 * v;
                myH[(quad * 4 + r) * 72 + n * 16 + col] = (_Float16)v;
            }
        // ---- GEMM2: D(16x64) = h1(16x64) @ W2, B from registers ----
        float4_t D[4] = {{0,0,0,0},{0,0,0,0},{0,0,0,0},{0,0,0,0}};
        #pragma unroll
        for (int ks = 0; ks < 2; ++ks) {
            const half8 af = *(const half8*)&myH[col * 72 + ks * 32 + quad * 8];
            #pragma unroll
            for (int n = 0; n < 4; ++n)
                D[n] = __builtin_amdgcn_mfma_f32_16x16x32_f16(af, w2f[ks][n], D[n], 0, 0, 0);
        }
        // layer3: +b2, PReLU(a2), dot W3; shfl-reduce 16 col lanes (b3 shift-invariant)
        float pr[4] = {0.f, 0.f, 0.f, 0.f};
        #pragma unroll
        for (int n = 0; n < 4; ++n)
            #pragma unroll
            for (int r = 0; r < 4; ++r) {
                float v = D[n][r] + b2reg[n];
                v = v >= 0.f ? v : pa2 * v;
                pr[r] += v * w3reg[n];
            }
        #pragma unroll
        for (int r = 0; r < 4; ++r) {
            float pv = pr[r];
            pv += __shfl_xor(pv, 1);
            pv += __shfl_xor(pv, 2);
            pv += __shfl_xor(pv, 4);
            pv += __shfl_xor(pv, 8);
            const int l = l0 + quad * 4 + r;
            if (col == 0 && l < len) sS[l] = pv;
        }
    }

    __syncthreads();
    // ---- masked softmax over sS[0..199] ----
    float m = (tid < LL) ? sS[tid] : -INFINITY;
    #pragma unroll
    for (int o = 1; o < 64; o <<= 1) m = fmaxf(m, __shfl_xor(m, o));
    if (lane == 0) sRed[wv] = m;
    __syncthreads();
    const float M = fmaxf(fmaxf(sRed[0], sRed[1]), fmaxf(sRed[2], sRed[3]));
    float e = (tid < LL) ? expf(sS[tid] - M) : 0.f;
    float s = e;
    #pragma unroll
    for (int o = 1; o < 64; o <<= 1) s += __shfl_xor(s, o);
    if (lane == 0) sRed[8 + wv] = s;
    __syncthreads();
    const float S = sRed[8] + sRed[9] + sRed[10] + sRed[11];
    const float inv = 1.f / S;
    if (tid < LL) {
        const float v = e * inv;
        sS[tid] = v;
        att[(size_t)b * LL + tid] = v;
    }
    __syncthreads();

    // ---- out[b][:] = sum_l att[l]*keys[l][:]  from sKeys fp16 ----
    {
        const int c8 = tid & 15, ph = tid >> 4;
        float acc[8];
        #pragma unroll
        for (int j = 0; j < 8; ++j) acc[j] = 0.f;
        for (int l = ph; l < Lcap; l += 16) {
            const float w = sS[l];
            const half8 kv = *(const half8*)&sKeys[l * DD + ((c8 ^ (l & 7)) << 3)];
            #pragma unroll
            for (int j = 0; j < 8; ++j) acc[j] += w * (float)kv[j];
        }
        float* const scratch = (float*)sWq;   // sWq dead after GEMM loop
        #pragma unroll
        for (int j = 0; j < 8; ++j) scratch[tid * 8 + j] = acc[j];
        __syncthreads();
        if (tid < DD) {
            const int c8o = tid >> 3, j = tid & 7;
            float r = 0.f;
            #pragma unroll
            for (int p = 0; p < 16; ++p) r += scratch[(p * 16 + c8o) * 8 + j];
            out[(size_t)b * DD + tid] = r;
        }
    }
}

extern "C" void kernel_launch(void* const* d_in, const int* in_sizes, int n_in,
                              void* d_out, int out_size, void* d_ws, size_t ws_size,
                              hipStream_t stream) {
    (void)in_sizes; (void)n_in; (void)ws_size; (void)out_size;
    const float* query = (const float*)d_in[0];
    const float* keys  = (const float*)d_in[1];
    const int*   klen  = (const int*)d_in[2];
    const float* W1    = (const float*)d_in[3];
    const float* b1    = (const float*)d_in[4];
    const float* a1    = (const float*)d_in[5];
    const float* W2    = (const float*)d_in[6];
    const float* b2    = (const float*)d_in[7];
    const float* a2    = (const float*)d_in[8];
    const float* W3    = (const float*)d_in[9];
    // d_in[10] = b3: irrelevant to both outputs (softmax shift invariance)

    _Float16* ws16 = (_Float16*)d_ws;
    float*    qawk = (float*)((char*)d_ws + WS_QA_OFF);

    float* out = (float*)d_out;                  // (B, D) fp32
    float* att = out + (size_t)NB * DD;          // (B, L) fp32

    hipLaunchKernelGGL(din_prep, dim3(130), dim3(256), 0, stream,
                       query, W1, b1, W2, ws16, qawk);
    hipLaunchKernelGGL(din_main, dim3(NB), dim3(256), 0, stream,
                       keys, klen, a1, b2, a2, W3, ws16, qawk, query, out, att);
}